// Round 3
// baseline (1001.815 us; speedup 1.0000x reference)
//
#include <hip/hip_runtime.h>
#include <math.h>

#define NN 100000      // nodes
#define NE 1600000     // edges
#define NG 512         // graphs
#define LN_EPS 1e-5f

typedef __attribute__((ext_vector_type(8))) short short8;
typedef __attribute__((ext_vector_type(4))) float floatx4;

union BF8U { short8 v; unsigned u[4]; };
union F4   { floatx4 v; float f[4]; };

// pack two f32 -> two bf16 in one u32 (round-half-up: 1 add/elem + 1 v_perm/pair)
static __device__ __forceinline__ unsigned pk_bf2(float a, float b) {
    union { float f; unsigned u; } A, B;
    A.f = a; B.f = b;
    const unsigned ua = A.u + 0x8000u;
    const unsigned ub = B.u + 0x8000u;
    return __builtin_amdgcn_perm(ub, ua, 0x07060302u);  // lo16=bf(a), hi16=bf(b)
}
static __device__ __forceinline__ float silu_f(float v) {
    return v * __builtin_amdgcn_rcpf(1.0f + __expf(-v));
}
// native global_atomic_add_f32
static __device__ __forceinline__ void atomf(float* p, float v) {
    unsafeAtomicAdd(p, v);
}

// ===========================================================================
// x -> bf16 pre-conversion (packed pairs; x_bf row = 32 uints = 128 B)
// ===========================================================================
__global__ __launch_bounds__(256)
void xconv_kernel(const float* __restrict__ x, unsigned* __restrict__ x_bf)
{
    const int total = NN * 32;
    for (int i = blockIdx.x * blockDim.x + threadIdx.x; i < total;
         i += gridDim.x * blockDim.x) {
        const float2 v = *(const float2*)(x + (size_t)i * 2);
        x_bf[i] = pk_bf2(v.x, v.y);
    }
}

// ===========================================================================
// Counting sort of edges by dst. Outputs (all in dst-sorted position space):
//   eid_s[pos]  = edge id     (consumed by eperm_kernel)
//   srcs_s[pos] = src node    (consumed by edge kernel x-gather)
//   dsts_s[pos] = dst node    (sorted ascending)
// After scatter, cnt[n] = end offset of node n.
// ===========================================================================
__global__ __launch_bounds__(256)
void hist_kernel(const int* __restrict__ dst, int* __restrict__ cnt)
{
    for (int e = blockIdx.x * blockDim.x + threadIdx.x; e < NE;
         e += gridDim.x * blockDim.x)
        atomicAdd(&cnt[dst[e]], 1);
}

#define SCAN_CHUNK 1024
#define SCAN_NB ((NN + SCAN_CHUNK - 1) / SCAN_CHUNK)   // 98

__global__ __launch_bounds__(256)
void scan_partial_kernel(const int* __restrict__ cnt, int* __restrict__ bsums)
{
    __shared__ int sdata[256];
    const int b = blockIdx.x, t = threadIdx.x;
    const int base = b * SCAN_CHUNK + t * 4;
    int s = 0;
    #pragma unroll
    for (int i = 0; i < 4; ++i) {
        const int idx = base + i;
        s += (idx < NN) ? cnt[idx] : 0;
    }
    sdata[t] = s;
    __syncthreads();
    for (int off = 128; off > 0; off >>= 1) {
        if (t < off) sdata[t] += sdata[t + off];
        __syncthreads();
    }
    if (t == 0) bsums[b] = sdata[0];
}

__global__ __launch_bounds__(128)
void scan_top_kernel(int* __restrict__ bsums)
{
    __shared__ int s[128];
    const int t = threadIdx.x;
    const int v = (t < SCAN_NB) ? bsums[t] : 0;
    s[t] = v;
    __syncthreads();
    for (int off = 1; off < 128; off <<= 1) {
        const int u = (t >= off) ? s[t - off] : 0;
        __syncthreads();
        s[t] += u;
        __syncthreads();
    }
    if (t < SCAN_NB) bsums[t] = s[t] - v;   // exclusive
}

__global__ __launch_bounds__(256)
void scan_final_kernel(int* __restrict__ cnt, const int* __restrict__ bsums)
{
    __shared__ int sdata[256];
    const int b = blockIdx.x, t = threadIdx.x;
    const int base = b * SCAN_CHUNK + t * 4;
    int c[4];
    #pragma unroll
    for (int i = 0; i < 4; ++i) {
        const int idx = base + i;
        c[i] = (idx < NN) ? cnt[idx] : 0;
    }
    const int tsum = c[0] + c[1] + c[2] + c[3];
    sdata[t] = tsum;
    __syncthreads();
    for (int off = 1; off < 256; off <<= 1) {
        const int v = (t >= off) ? sdata[t - off] : 0;
        __syncthreads();
        sdata[t] += v;
        __syncthreads();
    }
    int off0 = bsums[b] + sdata[t] - tsum;
    #pragma unroll
    for (int i = 0; i < 4; ++i) {
        const int idx = base + i;
        if (idx < NN) cnt[idx] = off0;
        off0 += c[i];
    }
}

__global__ __launch_bounds__(256)
void scatter_kernel(const int* __restrict__ src, const int* __restrict__ dst,
                    int* __restrict__ starts,
                    int* __restrict__ eid_s, int* __restrict__ srcs_s,
                    int* __restrict__ dsts_s)
{
    for (int e = blockIdx.x * blockDim.x + threadIdx.x; e < NE;
         e += gridDim.x * blockDim.x) {
        const int d = dst[e];
        const int pos = atomicAdd(&starts[d], 1);
        eid_s[pos]  = e;
        srcs_s[pos] = src[e];
        dsts_s[pos] = d;
    }
}

// ===========================================================================
// eperm: gather eattr rows in dst-sorted order, convert to bf16, and store in
// EXACT MFMA A-fragment order: eattr_s[tile][kh][lane] (16 B per slot).
// Lane l (m=l&15, q=l>>4) of tile tl holds edge (tl*16+m), k = kh*32+q*8+0..7
// as 4 packed-bf16 uints. Pure-BW kernel: the 410 MB random-row gather runs
// fully parallel here instead of gating the MFMA kernel's serial chain.
// ===========================================================================
#define EP_BLOCKS 2048
__global__ __launch_bounds__(256)
void eperm_kernel(const int* __restrict__ eid_s,
                  const float* __restrict__ eattr,
                  uint4* __restrict__ eattr_s)
{
    const int lane = threadIdx.x & 63;
    const int wid  = threadIdx.x >> 6;
    const int m = lane & 15;
    const int q = lane >> 4;
    const int n_tiles = NE / 16;
    const int nw = gridDim.x * 4;
    for (int tl = blockIdx.x * 4 + wid; tl < n_tiles; tl += nw) {
        const int eid = eid_s[tl * 16 + m];
        const float* p = eattr + (size_t)eid * 64 + q * 8;
        F4 u0, u1, u2, u3;
        u0.v = *(const floatx4*)p;        u1.v = *(const floatx4*)(p + 4);
        u2.v = *(const floatx4*)(p + 32); u3.v = *(const floatx4*)(p + 36);
        BF8U f0, f1;
        f0.u[0] = pk_bf2(u0.f[0], u0.f[1]);
        f0.u[1] = pk_bf2(u0.f[2], u0.f[3]);
        f0.u[2] = pk_bf2(u1.f[0], u1.f[1]);
        f0.u[3] = pk_bf2(u1.f[2], u1.f[3]);
        f1.u[0] = pk_bf2(u2.f[0], u2.f[1]);
        f1.u[1] = pk_bf2(u2.f[2], u2.f[3]);
        f1.u[2] = pk_bf2(u3.f[0], u3.f[1]);
        f1.u[3] = pk_bf2(u3.f[2], u3.f[3]);
        uint4* d4 = eattr_s + (size_t)tl * 128;
        d4[lane]      = *(uint4*)f0.u;   // kh = 0
        d4[64 + lane] = *(uint4*)f1.u;   // kh = 1
    }
}

// ===========================================================================
// Sorted edge kernel (streaming). Fixed tile partition; a1 fragments are two
// sequential 16B loads from eattr_s (zero repack). Exactly-once carry-merge
// flush: interior nodes -> plain stores; the wave's boundary dsts (bd0/bd1,
// the only nodes shareable with neighbor waves) -> native f32 atomics.
// mfma_f32_16x16x32_bf16: A/B idx=lane&15, k=(lane>>4)*8+j ; C/D col=lane&15,
// row=(lane>>4)*4+reg.
// ===========================================================================
#define EK_BLOCKS 2048
#define EK_WAVES (EK_BLOCKS * 4)

__global__ __launch_bounds__(256)
void edge_kernel_sorted(const unsigned* __restrict__ x_bf,
                        const int* __restrict__ srcs_s,
                        const int* __restrict__ dsts_s,
                        const uint4* __restrict__ eattr_s,
                        const float* __restrict__ We,
                        const float* __restrict__ be,
                        const float* __restrict__ Wm,
                        const float* __restrict__ bm,
                        float* __restrict__ agg)
{
    __shared__ float ltile[4][16 * 68];     // per-wave f32 16x64 tile, stride 68
    const int lane = threadIdx.x & 63;
    const int wid  = threadIdx.x >> 6;
    const int m = lane & 15;
    const int q = lane >> 4;
    float* tile = ltile[wid];

    // register-resident B-fragments of We, Wm
    short8 wef[2][4], wmf[2][4];
    float bev[4], bmv[4];
    #pragma unroll
    for (int kh = 0; kh < 2; ++kh)
        #pragma unroll
        for (int t = 0; t < 4; ++t) {
            BF8U fe, fm;
            #pragma unroll
            for (int p = 0; p < 4; ++p) {
                const int k = kh * 32 + q * 8 + p * 2;
                const int n = m + 16 * t;
                fe.u[p] = pk_bf2(We[k * 64 + n], We[(k + 1) * 64 + n]);
                fm.u[p] = pk_bf2(Wm[k * 64 + n], Wm[(k + 1) * 64 + n]);
            }
            wef[kh][t] = fe.v; wmf[kh][t] = fm.v;
        }
    #pragma unroll
    for (int t = 0; t < 4; ++t) { bev[t] = be[m + 16 * t]; bmv[t] = bm[m + 16 * t]; }

    const int n_tiles = NE / 16;                       // 100000 (exact)
    const int tpw = (n_tiles + EK_WAVES - 1) / EK_WAVES;
    const int w = blockIdx.x * 4 + wid;
    const int tl0 = w * tpw;
    const int tl1 = min(n_tiles, tl0 + tpw);
    if (tl0 >= tl1) return;

    // boundary dsts of this wave's range (shareable with neighbors -> atomic)
    const int bd0 = dsts_s[tl0 * 16];
    const int bd1 = dsts_s[tl1 * 16 - 1];

    // ---- prologue: src indices for tile0 & tile1; data for tile0 ----
    int srcB = srcs_s[tl0 * 16 + m];
    int srcC = (tl0 + 1 < tl1) ? srcs_s[(tl0 + 1) * 16 + m] : srcB;
    uint4 a1c0 = eattr_s[(size_t)tl0 * 128 + lane];
    uint4 a1c1 = eattr_s[(size_t)tl0 * 128 + 64 + lane];
    uint4 xa = *(const uint4*)(x_bf + (size_t)srcB * 32 + q * 4);
    uint4 xb = *(const uint4*)(x_bf + (size_t)srcB * 32 + 16 + q * 4);
    srcB = srcC;   // srcB now holds index for the NEXT tile's x prefetch

    float cv[4] = {0.f, 0.f, 0.f, 0.f};   // wave carry (replicated in all lanes)
    int cd = -1;

    for (int tl = tl0; tl < tl1; ++tl) {
        const bool haveNext = (tl + 1 < tl1);
        // ---- prefetch src indices 2 tiles ahead ----
        int srcN = srcB;
        if (tl + 2 < tl1) srcN = srcs_s[(tl + 2) * 16 + m];
        // ---- prefetch data for next tile (a1 seq stream + x gather) ----
        uint4 a1n0 = a1c0, a1n1 = a1c1, xan = xa, xbn = xb;
        if (haveNext) {
            a1n0 = eattr_s[(size_t)(tl + 1) * 128 + lane];
            a1n1 = eattr_s[(size_t)(tl + 1) * 128 + 64 + lane];
            xan = *(const uint4*)(x_bf + (size_t)srcB * 32 + q * 4);
            xbn = *(const uint4*)(x_bf + (size_t)srcB * 32 + 16 + q * 4);
        }
        // ---- dsts of my 4 rows (aligned int4, sequential) ----
        const int4 dnv = *(const int4*)&dsts_s[tl * 16 + q * 4];

        // ---- matmul 1: EA = edge_attr @ We (fragments pre-made by eperm) ----
        short8 a1[2];
        {
            BF8U t0, t1;
            *(uint4*)t0.u = a1c0; *(uint4*)t1.u = a1c1;
            a1[0] = t0.v; a1[1] = t1.v;
        }
        floatx4 acc[4];
        #pragma unroll
        for (int t = 0; t < 4; ++t) acc[t] = (floatx4){0.f, 0.f, 0.f, 0.f};
        #pragma unroll
        for (int kh = 0; kh < 2; ++kh)
            #pragma unroll
            for (int t = 0; t < 4; ++t)
                acc[t] = __builtin_amdgcn_mfma_f32_16x16x32_bf16(a1[kh], wef[kh][t], acc[t], 0, 0, 0);

        // silu+bias -> LDS (f32, C-layout -> row-major [edge][channel])
        #pragma unroll
        for (int t = 0; t < 4; ++t)
            #pragma unroll
            for (int r = 0; r < 4; ++r)
                tile[(q * 4 + r) * 68 + m + 16 * t] = silu_f(acc[t][r] + bev[t]);
        __asm__ volatile("s_waitcnt lgkmcnt(0)" ::: "memory");  // wave-sync RAW

        // ---- matmul 2: A = relu(x_bf[src] + EA) ----
        short8 a2[2];
        {
            const float* lp = &tile[m * 68 + q * 8];
            F4 A0, A1, B0, B1;
            A0.v = *(const floatx4*)lp;        A1.v = *(const floatx4*)(lp + 4);
            B0.v = *(const floatx4*)(lp + 32); B1.v = *(const floatx4*)(lp + 36);
            const unsigned xu[8] = {xa.x, xa.y, xa.z, xa.w, xb.x, xb.y, xb.z, xb.w};
            float el[16];
            el[0]=A0.f[0]; el[1]=A0.f[1]; el[2]=A0.f[2]; el[3]=A0.f[3];
            el[4]=A1.f[0]; el[5]=A1.f[1]; el[6]=A1.f[2]; el[7]=A1.f[3];
            el[8]=B0.f[0]; el[9]=B0.f[1]; el[10]=B0.f[2]; el[11]=B0.f[3];
            el[12]=B1.f[0]; el[13]=B1.f[1]; el[14]=B1.f[2]; el[15]=B1.f[3];
            BF8U f0, f1;
            #pragma unroll
            for (int p = 0; p < 8; ++p) {
                union { unsigned u; float f; } lo, hi;
                lo.u = xu[p] << 16; hi.u = xu[p] & 0xffff0000u;
                const float t0 = fmaxf(lo.f + el[p * 2],     0.0f);
                const float t1 = fmaxf(hi.f + el[p * 2 + 1], 0.0f);
                const unsigned pk = pk_bf2(t0, t1);
                if (p < 4) f0.u[p] = pk; else f1.u[p - 4] = pk;
            }
            a2[0] = f0.v; a2[1] = f1.v;
        }
        #pragma unroll
        for (int t = 0; t < 4; ++t) acc[t] = (floatx4){0.f, 0.f, 0.f, 0.f};
        #pragma unroll
        for (int kh = 0; kh < 2; ++kh)
            #pragma unroll
            for (int t = 0; t < 4; ++t)
                acc[t] = __builtin_amdgcn_mfma_f32_16x16x32_bf16(a2[kh], wmf[kh][t], acc[t], 0, 0, 0);

        float sv[4][4];
        #pragma unroll
        for (int t = 0; t < 4; ++t)
            #pragma unroll
            for (int r = 0; r < 4; ++r)
                sv[t][r] = silu_f(acc[t][r] + bmv[t]);

        // ---- exactly-once segmented flush: store interior, atomic boundary ----
        const int dn[4] = {dnv.x, dnv.y, dnv.z, dnv.w};
        #define FLUSH(DN, VAL)                                                  \
            do { if ((DN) >= 0) {                                               \
                float* _p = agg + (size_t)(DN) * 64 + m;                        \
                if ((DN) == bd0 || (DN) == bd1) {                               \
                    atomf(_p,      (VAL)[0]); atomf(_p + 16, (VAL)[1]);         \
                    atomf(_p + 32, (VAL)[2]); atomf(_p + 48, (VAL)[3]);         \
                } else {                                                        \
                    _p[0]  = (VAL)[0]; _p[16] = (VAL)[1];                       \
                    _p[32] = (VAL)[2]; _p[48] = (VAL)[3];                       \
                } } } while (0)

        // within-lane chain over rows q*4 .. q*4+3
        float run[4], head[4] = {0.f, 0.f, 0.f, 0.f};
        const int hd = dn[0];
        int rd = dn[0];
        bool headClosed = false;
        #pragma unroll
        for (int t = 0; t < 4; ++t) run[t] = sv[t][0];
        #pragma unroll
        for (int r = 1; r < 4; ++r) {
            if (dn[r] == rd) {
                #pragma unroll
                for (int t = 0; t < 4; ++t) run[t] += sv[t][r];
            } else {
                if (!headClosed) {
                    #pragma unroll
                    for (int t = 0; t < 4; ++t) head[t] = run[t];
                    headClosed = true;
                } else {
                    FLUSH(rd, run);              // interior run
                }
                #pragma unroll
                for (int t = 0; t < 4; ++t) run[t] = sv[t][r];
                rd = dn[r];
            }
        }
        const bool pure = !headClosed;           // whole 4-row group is one run
        float tail[4]; const int td = rd;
        #pragma unroll
        for (int t = 0; t < 4; ++t) tail[t] = run[t];

        // cross-q-group merge, sequential g=0..3 (run structure wave-uniform)
        float tl_[4]; int td_;
        #pragma unroll
        for (int t = 0; t < 4; ++t) tl_[t] = tail[t];
        td_ = td;
        #pragma unroll
        for (int g = 0; g < 4; ++g) {
            float iv[4]; int ivd;
            if (g == 0) {
                #pragma unroll
                for (int t = 0; t < 4; ++t) iv[t] = cv[t];
                ivd = cd;
            } else {
                const int sl = m + (g - 1) * 16;
                #pragma unroll
                for (int t = 0; t < 4; ++t) iv[t] = __shfl(tl_[t], sl, 64);
                ivd = __shfl(td_, (g - 1) * 16, 64);
            }
            const int hdg = __shfl(hd, g * 16, 64);
            const bool mine = (q == g);
            if (ivd == hdg) {
                if (mine) {
                    if (pure) {
                        #pragma unroll
                        for (int t = 0; t < 4; ++t) tl_[t] += iv[t];
                    } else {
                        #pragma unroll
                        for (int t = 0; t < 4; ++t) head[t] += iv[t];
                    }
                }
            } else {
                if (g == 0) {
                    if (q == 0) FLUSH(cd, iv);
                } else {
                    if (q == g - 1) FLUSH(td_, tl_);
                }
            }
            if (mine && !pure) FLUSH(hd, head);
        }
        // new carry = tail of group 3
        #pragma unroll
        for (int t = 0; t < 4; ++t) cv[t] = __shfl(tl_[t], m + 48, 64);
        cd = __shfl(td_, 48, 64);

        // rotate prefetched state
        a1c0 = a1n0; a1c1 = a1n1;
        xa = xan; xb = xbn;
        srcB = srcN;
    }
    // final carry flush (cd == bd1 -> atomic path inside FLUSH)
    if (q == 0 && cd >= 0) {
        float* _p = agg + (size_t)cd * 64 + m;
        if (cd == bd0 || cd == bd1) {
            atomf(_p, cv[0]); atomf(_p + 16, cv[1]);
            atomf(_p + 32, cv[2]); atomf(_p + 48, cv[3]);
        } else {
            _p[0] = cv[0]; _p[16] = cv[1]; _p[32] = cv[2]; _p[48] = cv[3];
        }
    }
    #undef FLUSH
}

// ===========================================================================
// Fallback (ws too small): unsorted, plain atomics.
// ===========================================================================
__global__ __launch_bounds__(256)
void edge_kernel_unsorted(const float* __restrict__ x,
                          const int* __restrict__ src,
                          const int* __restrict__ dst,
                          const float* __restrict__ eattr,
                          const float* __restrict__ We,
                          const float* __restrict__ be,
                          const float* __restrict__ Wm,
                          const float* __restrict__ bm,
                          float* __restrict__ agg)
{
    __shared__ float ltile[4][16 * 68];
    const int lane = threadIdx.x & 63;
    const int wid  = threadIdx.x >> 6;
    const int m = lane & 15;
    const int q = lane >> 4;
    float* tile = ltile[wid];

    short8 wef[2][4], wmf[2][4];
    float bev[4], bmv[4];
    #pragma unroll
    for (int kh = 0; kh < 2; ++kh)
        #pragma unroll
        for (int t = 0; t < 4; ++t) {
            BF8U fe, fm;
            #pragma unroll
            for (int p = 0; p < 4; ++p) {
                const int k = kh * 32 + q * 8 + p * 2;
                const int n = m + 16 * t;
                fe.u[p] = pk_bf2(We[k * 64 + n], We[(k + 1) * 64 + n]);
                fm.u[p] = pk_bf2(Wm[k * 64 + n], Wm[(k + 1) * 64 + n]);
            }
            wef[kh][t] = fe.v; wmf[kh][t] = fm.v;
        }
    #pragma unroll
    for (int t = 0; t < 4; ++t) { bev[t] = be[m + 16 * t]; bmv[t] = bm[m + 16 * t]; }

    const int n_tiles = NE / 16;
    const int stride = gridDim.x * 4;
    for (int tl = blockIdx.x * 4 + wid; tl < n_tiles; tl += stride) {
        const int e0 = tl * 16;
        short8 a1[2];
        #pragma unroll
        for (int kh = 0; kh < 2; ++kh) {
            const float* p = eattr + (size_t)(e0 + m) * 64 + kh * 32 + q * 8;
            F4 v0, v1; v0.v = *(const floatx4*)p; v1.v = *(const floatx4*)(p + 4);
            BF8U f;
            f.u[0] = pk_bf2(v0.f[0], v0.f[1]);
            f.u[1] = pk_bf2(v0.f[2], v0.f[3]);
            f.u[2] = pk_bf2(v1.f[0], v1.f[1]);
            f.u[3] = pk_bf2(v1.f[2], v1.f[3]);
            a1[kh] = f.v;
        }
        floatx4 acc[4];
        #pragma unroll
        for (int t = 0; t < 4; ++t) acc[t] = (floatx4){0.f, 0.f, 0.f, 0.f};
        #pragma unroll
        for (int kh = 0; kh < 2; ++kh)
            #pragma unroll
            for (int t = 0; t < 4; ++t)
                acc[t] = __builtin_amdgcn_mfma_f32_16x16x32_bf16(a1[kh], wef[kh][t], acc[t], 0, 0, 0);
        #pragma unroll
        for (int t = 0; t < 4; ++t)
            #pragma unroll
            for (int r = 0; r < 4; ++r)
                tile[(q * 4 + r) * 68 + m + 16 * t] = silu_f(acc[t][r] + bev[t]);
        __asm__ volatile("s_waitcnt lgkmcnt(0)" ::: "memory");
        const int sn = src[e0 + m];
        short8 a2[2];
        {
            const float* lp = &tile[m * 68 + q * 8];
            const float* xp = x + (size_t)sn * 64 + q * 8;
            F4 a, b, c, d, X0, X1, X2, X3;
            a.v = *(const floatx4*)lp;        b.v = *(const floatx4*)(lp + 4);
            c.v = *(const floatx4*)(lp + 32); d.v = *(const floatx4*)(lp + 36);
            X0.v = *(const floatx4*)xp;        X1.v = *(const floatx4*)(xp + 4);
            X2.v = *(const floatx4*)(xp + 32); X3.v = *(const floatx4*)(xp + 36);
            BF8U f0, f1;
            f0.u[0] = pk_bf2(fmaxf(a.f[0]+X0.f[0],0.f), fmaxf(a.f[1]+X0.f[1],0.f));
            f0.u[1] = pk_bf2(fmaxf(a.f[2]+X0.f[2],0.f), fmaxf(a.f[3]+X0.f[3],0.f));
            f0.u[2] = pk_bf2(fmaxf(b.f[0]+X1.f[0],0.f), fmaxf(b.f[1]+X1.f[1],0.f));
            f0.u[3] = pk_bf2(fmaxf(b.f[2]+X1.f[2],0.f), fmaxf(b.f[3]+X1.f[3],0.f));
            f1.u[0] = pk_bf2(fmaxf(c.f[0]+X2.f[0],0.f), fmaxf(c.f[1]+X2.f[1],0.f));
            f1.u[1] = pk_bf2(fmaxf(c.f[2]+X2.f[2],0.f), fmaxf(c.f[3]+X2.f[3],0.f));
            f1.u[2] = pk_bf2(fmaxf(d.f[0]+X3.f[0],0.f), fmaxf(d.f[1]+X3.f[1],0.f));
            f1.u[3] = pk_bf2(fmaxf(d.f[2]+X3.f[2],0.f), fmaxf(d.f[3]+X3.f[3],0.f));
            a2[0] = f0.v; a2[1] = f1.v;
        }
        #pragma unroll
        for (int t = 0; t < 4; ++t) acc[t] = (floatx4){0.f, 0.f, 0.f, 0.f};
        #pragma unroll
        for (int kh = 0; kh < 2; ++kh)
            #pragma unroll
            for (int t = 0; t < 4; ++t)
                acc[t] = __builtin_amdgcn_mfma_f32_16x16x32_bf16(a2[kh], wmf[kh][t], acc[t], 0, 0, 0);
        int dn[4];
        #pragma unroll
        for (int r = 0; r < 4; ++r) dn[r] = dst[e0 + q * 4 + r];
        #pragma unroll
        for (int t = 0; t < 4; ++t)
            #pragma unroll
            for (int r = 0; r < 4; ++r)
                atomf(agg + (size_t)dn[r] * 64 + m + 16 * t, silu_f(acc[t][r] + bmv[t]));
    }
}

// ===========================================================================
// Stats: per-graph sum/sumsq/count over pre = agg + (1+eps)*x (n2g sorted).
// ===========================================================================
#define STATS_WAVES 4096
__global__ __launch_bounds__(256)
void stats_kernel(const float* __restrict__ agg,
                  const float* __restrict__ x,
                  const int* __restrict__ n2g,
                  const float* __restrict__ eps,
                  float* __restrict__ gsum,
                  float* __restrict__ gss,
                  float* __restrict__ gcnt)
{
    const int lane = threadIdx.x & 63;
    const int wid  = threadIdx.x >> 6;
    const int w    = blockIdx.x * 4 + wid;
    const int chunk = (NN + STATS_WAVES - 1) / STATS_WAVES;
    const int n0 = w * chunk;
    const int n1 = min(NN, n0 + chunk);
    if (n0 >= n1) return;
    const float k = 1.0f + eps[0];

    int   curg = n2g[n0];
    float s = 0.f, ss = 0.f, rc = 0.f;
    for (int n = n0; n < n1; ++n) {
        const int g = n2g[n];
        if (g != curg) {
            float a = s, b = ss;
            #pragma unroll
            for (int off = 32; off > 0; off >>= 1) {
                a += __shfl_down(a, off, 64);
                b += __shfl_down(b, off, 64);
            }
            if (lane == 0) {
                atomf(&gsum[curg], a);
                atomf(&gss[curg], b);
                atomf(&gcnt[curg], rc);
            }
            s = 0.f; ss = 0.f; rc = 0.f; curg = g;
        }
        const float pre = agg[(size_t)n * 64 + lane] + k * x[(size_t)n * 64 + lane];
        s += pre; ss += pre * pre; rc += (lane == 0) ? 1.0f : 0.0f;
    }
    float a = s, b = ss;
    #pragma unroll
    for (int off = 32; off > 0; off >>= 1) {
        a += __shfl_down(a, off, 64);
        b += __shfl_down(b, off, 64);
    }
    if (lane == 0) {
        atomf(&gsum[curg], a);
        atomf(&gss[curg], b);
        atomf(&gcnt[curg], rc);
    }
}

// ===========================================================================
// Norm + residual + relu, in place over agg (== d_out).
// ===========================================================================
__global__ __launch_bounds__(256)
void norm_kernel(const float* __restrict__ x,
                 const int* __restrict__ n2g,
                 const float* __restrict__ eps,
                 const float* __restrict__ gamma,
                 const float* __restrict__ beta,
                 const float* __restrict__ gsum,
                 const float* __restrict__ gss,
                 const float* __restrict__ gcnt,
                 float* __restrict__ out)
{
    const float k = 1.0f + eps[0];
    const int total = NN * 16;
    for (int idx = blockIdx.x * blockDim.x + threadIdx.x; idx < total;
         idx += gridDim.x * blockDim.x) {
        const int n  = idx >> 4;
        const int c4 = (idx & 15) * 4;
        const int g  = n2g[n];
        const float cnt  = fmaxf(gcnt[g] * 64.0f, 1.0f);
        const float mean = gsum[g] / cnt;
        const float var  = gss[g] / cnt - mean * mean;
        const float rsig = rsqrtf(var + LN_EPS);
        F4 a, xv, o;
        a.v  = *(const floatx4*)&out[(size_t)n * 64 + c4];
        xv.v = *(const floatx4*)&x[(size_t)n * 64 + c4];
        #pragma unroll
        for (int j = 0; j < 4; ++j) {
            const float pre = a.f[j] + k * xv.f[j];
            const float v = (pre - mean) * rsig * gamma[c4 + j] + beta[c4 + j] + xv.f[j];
            o.f[j] = fmaxf(v, 0.0f);
        }
        *(floatx4*)&out[(size_t)n * 64 + c4] = o.v;
    }
}

extern "C" void kernel_launch(void* const* d_in, const int* in_sizes, int n_in,
                              void* d_out, int out_size, void* d_ws, size_t ws_size,
                              hipStream_t stream)
{
    const float* x      = (const float*)d_in[0];
    const int*   ei     = (const int*)  d_in[1];
    const float* eattr  = (const float*)d_in[2];
    const int*   n2g    = (const int*)  d_in[3];
    // branch-1 params (d_in[4..10]) are dead: conv1's result is overwritten by
    // conv2(x, ...) in the reference. Only branch 2 affects the output.
    const float* We2    = (const float*)d_in[11];
    const float* be2    = (const float*)d_in[12];
    const float* Wm2    = (const float*)d_in[13];
    const float* bm2    = (const float*)d_in[14];
    const float* eps2   = (const float*)d_in[15];
    const float* gamma2 = (const float*)d_in[16];
    const float* beta2  = (const float*)d_in[17];
    const int* src = ei;
    const int* dst = ei + NE;

    float* out  = (float*)d_out;           // doubles as agg scratch
    // ws (4B words): gsum[512] gss[512] gcnt[512] | bsums[128] | cnt[NN]
    //   | dsts_s[NE] | eid_s[NE] | srcs_s[NE] | x_bf[NN*32] | eattr_s[NE*32]
    float* gsum = (float*)d_ws;
    float* gss  = gsum + NG;
    float* gcnt = gss + NG;
    int*  bsums  = (int*)(gcnt + NG);
    int*  cnt    = bsums + 128;
    int*  dsts_s = cnt + NN;
    int*  eid_s  = dsts_s + NE;
    int*  srcs_s = eid_s + NE;
    unsigned* x_bf = (unsigned*)(srcs_s + NE);
    uint4* eattr_s = (uint4*)(x_bf + (size_t)NN * 32);
    const size_t ws_need = (size_t)(3 * NG + 128 + NN + 3 * (size_t)NE
                                    + (size_t)NN * 32 + (size_t)NE * 32) * 4;
    const bool do_sort = ws_size >= ws_need;

    hipMemsetAsync(d_out, 0, (size_t)NN * 64 * sizeof(float), stream);
    if (do_sort) {
        hipMemsetAsync(d_ws, 0, (size_t)(3 * NG + 128 + NN) * 4, stream);
        xconv_kernel<<<dim3(512), dim3(256), 0, stream>>>(x, x_bf);
        hist_kernel<<<dim3(512), dim3(256), 0, stream>>>(dst, cnt);
        scan_partial_kernel<<<dim3(SCAN_NB), dim3(256), 0, stream>>>(cnt, bsums);
        scan_top_kernel<<<dim3(1), dim3(128), 0, stream>>>(bsums);
        scan_final_kernel<<<dim3(SCAN_NB), dim3(256), 0, stream>>>(cnt, bsums);
        scatter_kernel<<<dim3(512), dim3(256), 0, stream>>>(src, dst, cnt,
                                                            eid_s, srcs_s, dsts_s);
        eperm_kernel<<<dim3(EP_BLOCKS), dim3(256), 0, stream>>>(eid_s, eattr, eattr_s);
        edge_kernel_sorted<<<dim3(EK_BLOCKS), dim3(256), 0, stream>>>(
            x_bf, srcs_s, dsts_s, eattr_s, We2, be2, Wm2, bm2, out);
    } else {
        hipMemsetAsync(d_ws, 0, 3 * NG * sizeof(float), stream);
        edge_kernel_unsorted<<<dim3(2048), dim3(256), 0, stream>>>(
            x, src, dst, eattr, We2, be2, Wm2, bm2, out);
    }
    stats_kernel<<<dim3(STATS_WAVES / 4), dim3(256), 0, stream>>>(
        out, x, n2g, eps2, gsum, gss, gcnt);
    norm_kernel<<<dim3(1024), dim3(256), 0, stream>>>(
        x, n2g, eps2, gamma2, beta2, gsum, gss, gcnt, out);
}

// Round 4
// 909.018 us; speedup vs baseline: 1.1021x; 1.1021x over previous
//
#include <hip/hip_runtime.h>
#include <math.h>

#define NN 100000      // nodes
#define NE 1600000     // edges
#define NG 512         // graphs
#define LN_EPS 1e-5f

typedef __attribute__((ext_vector_type(8))) short short8;
typedef __attribute__((ext_vector_type(4))) float floatx4;

union BF8U { short8 v; unsigned u[4]; };
union F4   { floatx4 v; float f[4]; };

// pack two f32 -> two bf16 in one u32 (round-half-up: 1 add/elem + 1 v_perm/pair)
static __device__ __forceinline__ unsigned pk_bf2(float a, float b) {
    union { float f; unsigned u; } A, B;
    A.f = a; B.f = b;
    const unsigned ua = A.u + 0x8000u;
    const unsigned ub = B.u + 0x8000u;
    return __builtin_amdgcn_perm(ub, ua, 0x07060302u);  // lo16=bf(a), hi16=bf(b)
}
static __device__ __forceinline__ float silu_f(float v) {
    return v * __builtin_amdgcn_rcpf(1.0f + __expf(-v));
}
// native global_atomic_add_f32 (never CAS-loop)
static __device__ __forceinline__ void atomf(float* p, float v) {
    unsafeAtomicAdd(p, v);
}

// ===========================================================================
// Fused: x -> bf16 pre-conversion  +  dst histogram (independent streams,
// one dispatch instead of two).
// ===========================================================================
__global__ __launch_bounds__(256)
void xconv_hist_kernel(const float* __restrict__ x, unsigned* __restrict__ x_bf,
                       const int* __restrict__ dst, int* __restrict__ cnt)
{
    const int tid = blockIdx.x * blockDim.x + threadIdx.x;
    const int stride = gridDim.x * blockDim.x;
    const int total = NN * 32;
    for (int i = tid; i < total; i += stride) {
        const float2 v = *(const float2*)(x + (size_t)i * 2);
        x_bf[i] = pk_bf2(v.x, v.y);
    }
    for (int e = tid; e < NE; e += stride)
        atomicAdd(&cnt[dst[e]], 1);
}

// ===========================================================================
// Counting sort of edges by dst. Outputs:
//   ps[pos]    = {edge_id, src}  (int2, coalesced reads in edge kernel)
//   dsts_s[pos]= dst             (sorted ascending)
// ===========================================================================
#define SCAN_CHUNK 1024
#define SCAN_NB ((NN + SCAN_CHUNK - 1) / SCAN_CHUNK)   // 98

__global__ __launch_bounds__(256)
void scan_partial_kernel(const int* __restrict__ cnt, int* __restrict__ bsums)
{
    __shared__ int sdata[256];
    const int b = blockIdx.x, t = threadIdx.x;
    const int base = b * SCAN_CHUNK + t * 4;
    int s = 0;
    #pragma unroll
    for (int i = 0; i < 4; ++i) {
        const int idx = base + i;
        s += (idx < NN) ? cnt[idx] : 0;
    }
    sdata[t] = s;
    __syncthreads();
    for (int off = 128; off > 0; off >>= 1) {
        if (t < off) sdata[t] += sdata[t + off];
        __syncthreads();
    }
    if (t == 0) bsums[b] = sdata[0];
}

__global__ __launch_bounds__(128)
void scan_top_kernel(int* __restrict__ bsums)
{
    __shared__ int s[128];
    const int t = threadIdx.x;
    const int v = (t < SCAN_NB) ? bsums[t] : 0;
    s[t] = v;
    __syncthreads();
    for (int off = 1; off < 128; off <<= 1) {
        const int u = (t >= off) ? s[t - off] : 0;
        __syncthreads();
        s[t] += u;
        __syncthreads();
    }
    if (t < SCAN_NB) bsums[t] = s[t] - v;   // exclusive
}

__global__ __launch_bounds__(256)
void scan_final_kernel(int* __restrict__ cnt, const int* __restrict__ bsums)
{
    __shared__ int sdata[256];
    const int b = blockIdx.x, t = threadIdx.x;
    const int base = b * SCAN_CHUNK + t * 4;
    int c[4];
    #pragma unroll
    for (int i = 0; i < 4; ++i) {
        const int idx = base + i;
        c[i] = (idx < NN) ? cnt[idx] : 0;
    }
    const int tsum = c[0] + c[1] + c[2] + c[3];
    sdata[t] = tsum;
    __syncthreads();
    for (int off = 1; off < 256; off <<= 1) {
        const int v = (t >= off) ? sdata[t - off] : 0;
        __syncthreads();
        sdata[t] += v;
        __syncthreads();
    }
    int off0 = bsums[b] + sdata[t] - tsum;
    #pragma unroll
    for (int i = 0; i < 4; ++i) {
        const int idx = base + i;
        if (idx < NN) cnt[idx] = off0;
        off0 += c[i];
    }
}

__global__ __launch_bounds__(256)
void scatter_kernel(const int* __restrict__ src, const int* __restrict__ dst,
                    int* __restrict__ starts,
                    int2* __restrict__ ps, int* __restrict__ dsts_s)
{
    for (int e = blockIdx.x * blockDim.x + threadIdx.x; e < NE;
         e += gridDim.x * blockDim.x) {
        const int d = dst[e];
        const int pos = atomicAdd(&starts[d], 1);
        ps[pos] = make_int2(e, src[e]);
        dsts_s[pos] = d;
    }
}

// ===========================================================================
// Sorted edge kernel (round-0 proven structure). Wave owns a contiguous run
// of 16-edge tiles (dst ascending): MFMA1 (eattr@We) -> silu -> LDS C->A
// transform -> add bf16-x, relu -> MFMA2 (@Wm) -> silu -> exact segmented
// reduction over dst runs (within-lane chain + cross-q shuffle merge +
// cross-tile wave carry), flushed with NATIVE f32 atomics (~1 per node).
// 2-deep index pipeline: ps indices 2 tiles ahead, eattr/x data 1 tile ahead.
// mfma_f32_16x16x32_bf16: A/B idx=lane&15, k=(lane>>4)*8+j ; C/D col=lane&15,
// row=(lane>>4)*4+reg.
// ===========================================================================
#define EK_BLOCKS 2048
#define EK_WAVES (EK_BLOCKS * 4)

__global__ __launch_bounds__(256)
void edge_kernel_sorted(const unsigned* __restrict__ x_bf,
                        const int2* __restrict__ ps,
                        const int* __restrict__ dsts_s,
                        const float* __restrict__ eattr,
                        const float* __restrict__ We,
                        const float* __restrict__ be,
                        const float* __restrict__ Wm,
                        const float* __restrict__ bm,
                        float* __restrict__ agg)
{
    __shared__ float ltile[4][16 * 68];     // per-wave f32 16x64 tile, stride 68
    const int lane = threadIdx.x & 63;
    const int wid  = threadIdx.x >> 6;
    const int m = lane & 15;
    const int q = lane >> 4;
    float* tile = ltile[wid];

    // register-resident B-fragments of We, Wm
    short8 wef[2][4], wmf[2][4];
    float bev[4], bmv[4];
    #pragma unroll
    for (int kh = 0; kh < 2; ++kh)
        #pragma unroll
        for (int t = 0; t < 4; ++t) {
            BF8U fe, fm;
            #pragma unroll
            for (int p = 0; p < 4; ++p) {
                const int k = kh * 32 + q * 8 + p * 2;
                const int n = m + 16 * t;
                fe.u[p] = pk_bf2(We[k * 64 + n], We[(k + 1) * 64 + n]);
                fm.u[p] = pk_bf2(Wm[k * 64 + n], Wm[(k + 1) * 64 + n]);
            }
            wef[kh][t] = fe.v; wmf[kh][t] = fm.v;
        }
    #pragma unroll
    for (int t = 0; t < 4; ++t) { bev[t] = be[m + 16 * t]; bmv[t] = bm[m + 16 * t]; }

    const int n_tiles = NE / 16;
    const int tpw = (n_tiles + EK_WAVES - 1) / EK_WAVES;
    const int w = blockIdx.x * 4 + wid;
    const int tl0 = w * tpw;
    const int tl1 = min(n_tiles, tl0 + tpw);
    if (tl0 >= tl1) return;

    // ---- prologue: indices for tile0 & tile1; data for tile0 ----
    int2 pvB = ps[tl0 * 16 + m];                                 // tile tl0
    int2 pvC = (tl0 + 1 < tl1) ? ps[(tl0 + 1) * 16 + m] : pvB;   // tile tl0+1
    floatx4 ea[4];
    {
        const float* p = eattr + (size_t)pvB.x * 64 + q * 8;
        ea[0] = *(const floatx4*)p;        ea[1] = *(const floatx4*)(p + 4);
        ea[2] = *(const floatx4*)(p + 32); ea[3] = *(const floatx4*)(p + 36);
    }
    uint4 xa = *(const uint4*)(x_bf + (size_t)pvB.y * 32 + q * 4);
    uint4 xb = *(const uint4*)(x_bf + (size_t)pvB.y * 32 + 16 + q * 4);
    pvB = pvC;   // pvB now holds indices for the NEXT tile's data prefetch

    float cv[4] = {0.f, 0.f, 0.f, 0.f};   // wave carry (replicated in all lanes)
    int cd = -1;

    for (int tl = tl0; tl < tl1; ++tl) {
        const bool haveNext = (tl + 1 < tl1);
        // ---- prefetch indices 2 tiles ahead (independent of in-flight data) ----
        int2 pvN = pvB;
        if (tl + 2 < tl1) pvN = ps[(tl + 2) * 16 + m];
        // ---- prefetch data for next tile from already-resident pvB ----
        floatx4 ean[4]; uint4 xan = xa, xbn = xb;
        if (haveNext) {
            const float* p = eattr + (size_t)pvB.x * 64 + q * 8;
            ean[0] = *(const floatx4*)p;        ean[1] = *(const floatx4*)(p + 4);
            ean[2] = *(const floatx4*)(p + 32); ean[3] = *(const floatx4*)(p + 36);
            xan = *(const uint4*)(x_bf + (size_t)pvB.y * 32 + q * 4);
            xbn = *(const uint4*)(x_bf + (size_t)pvB.y * 32 + 16 + q * 4);
        }
        // ---- dsts of my 4 rows (aligned int4, sequential) ----
        const int4 dnv = *(const int4*)&dsts_s[tl * 16 + q * 4];

        // ---- matmul 1: EA = edge_attr @ We ----
        short8 a1[2];
        {
            F4 u0, u1, u2, u3;
            u0.v = ea[0]; u1.v = ea[1]; u2.v = ea[2]; u3.v = ea[3];
            BF8U f0, f1;
            f0.u[0] = pk_bf2(u0.f[0], u0.f[1]);
            f0.u[1] = pk_bf2(u0.f[2], u0.f[3]);
            f0.u[2] = pk_bf2(u1.f[0], u1.f[1]);
            f0.u[3] = pk_bf2(u1.f[2], u1.f[3]);
            f1.u[0] = pk_bf2(u2.f[0], u2.f[1]);
            f1.u[1] = pk_bf2(u2.f[2], u2.f[3]);
            f1.u[2] = pk_bf2(u3.f[0], u3.f[1]);
            f1.u[3] = pk_bf2(u3.f[2], u3.f[3]);
            a1[0] = f0.v; a1[1] = f1.v;
        }
        floatx4 acc[4];
        #pragma unroll
        for (int t = 0; t < 4; ++t) acc[t] = (floatx4){0.f, 0.f, 0.f, 0.f};
        #pragma unroll
        for (int kh = 0; kh < 2; ++kh)
            #pragma unroll
            for (int t = 0; t < 4; ++t)
                acc[t] = __builtin_amdgcn_mfma_f32_16x16x32_bf16(a1[kh], wef[kh][t], acc[t], 0, 0, 0);

        // silu+bias -> LDS (f32, C-layout -> row-major [edge][channel])
        #pragma unroll
        for (int t = 0; t < 4; ++t)
            #pragma unroll
            for (int r = 0; r < 4; ++r)
                tile[(q * 4 + r) * 68 + m + 16 * t] = silu_f(acc[t][r] + bev[t]);
        __asm__ volatile("s_waitcnt lgkmcnt(0)" ::: "memory");  // wave-sync RAW

        // ---- matmul 2: A = relu(x_bf[src] + EA) ----
        short8 a2[2];
        {
            const float* lp = &tile[m * 68 + q * 8];
            F4 A0, A1, B0, B1;
            A0.v = *(const floatx4*)lp;        A1.v = *(const floatx4*)(lp + 4);
            B0.v = *(const floatx4*)(lp + 32); B1.v = *(const floatx4*)(lp + 36);
            const unsigned xu[8] = {xa.x, xa.y, xa.z, xa.w, xb.x, xb.y, xb.z, xb.w};
            float el[16];
            el[0]=A0.f[0]; el[1]=A0.f[1]; el[2]=A0.f[2]; el[3]=A0.f[3];
            el[4]=A1.f[0]; el[5]=A1.f[1]; el[6]=A1.f[2]; el[7]=A1.f[3];
            el[8]=B0.f[0]; el[9]=B0.f[1]; el[10]=B0.f[2]; el[11]=B0.f[3];
            el[12]=B1.f[0]; el[13]=B1.f[1]; el[14]=B1.f[2]; el[15]=B1.f[3];
            BF8U f0, f1;
            #pragma unroll
            for (int p = 0; p < 8; ++p) {
                union { unsigned u; float f; } lo, hi;
                lo.u = xu[p] << 16; hi.u = xu[p] & 0xffff0000u;
                const float t0 = fmaxf(lo.f + el[p * 2],     0.0f);
                const float t1 = fmaxf(hi.f + el[p * 2 + 1], 0.0f);
                const unsigned pk = pk_bf2(t0, t1);
                if (p < 4) f0.u[p] = pk; else f1.u[p - 4] = pk;
            }
            a2[0] = f0.v; a2[1] = f1.v;
        }
        #pragma unroll
        for (int t = 0; t < 4; ++t) acc[t] = (floatx4){0.f, 0.f, 0.f, 0.f};
        #pragma unroll
        for (int kh = 0; kh < 2; ++kh)
            #pragma unroll
            for (int t = 0; t < 4; ++t)
                acc[t] = __builtin_amdgcn_mfma_f32_16x16x32_bf16(a2[kh], wmf[kh][t], acc[t], 0, 0, 0);

        float sv[4][4];
        #pragma unroll
        for (int t = 0; t < 4; ++t)
            #pragma unroll
            for (int r = 0; r < 4; ++r)
                sv[t][r] = silu_f(acc[t][r] + bmv[t]);

        // ---- segmented flush (exact; ~1 native atomic per node) ----
        const int dn[4] = {dnv.x, dnv.y, dnv.z, dnv.w};
        #define FLUSH(DN, VAL)                                                  \
            do {                                                                \
                atomf(agg + (size_t)(DN) * 64 + m,      (VAL)[0]);              \
                atomf(agg + (size_t)(DN) * 64 + m + 16, (VAL)[1]);              \
                atomf(agg + (size_t)(DN) * 64 + m + 32, (VAL)[2]);              \
                atomf(agg + (size_t)(DN) * 64 + m + 48, (VAL)[3]);              \
            } while (0)

        // within-lane chain over rows q*4 .. q*4+3
        float run[4], head[4] = {0.f, 0.f, 0.f, 0.f};
        const int hd = dn[0];
        int rd = dn[0];
        bool headClosed = false;
        #pragma unroll
        for (int t = 0; t < 4; ++t) run[t] = sv[t][0];
        #pragma unroll
        for (int r = 1; r < 4; ++r) {
            if (dn[r] == rd) {
                #pragma unroll
                for (int t = 0; t < 4; ++t) run[t] += sv[t][r];
            } else {
                if (!headClosed) {
                    #pragma unroll
                    for (int t = 0; t < 4; ++t) head[t] = run[t];
                    headClosed = true;
                } else {
                    FLUSH(rd, run);              // interior run
                }
                #pragma unroll
                for (int t = 0; t < 4; ++t) run[t] = sv[t][r];
                rd = dn[r];
            }
        }
        const bool pure = !headClosed;           // whole 4-row group is one run
        float tail[4]; const int td = rd;
        #pragma unroll
        for (int t = 0; t < 4; ++t) tail[t] = run[t];

        // cross-q-group merge, sequential g=0..3 (run structure wave-uniform)
        float tl_[4]; int td_;
        #pragma unroll
        for (int t = 0; t < 4; ++t) tl_[t] = tail[t];
        td_ = td;
        #pragma unroll
        for (int g = 0; g < 4; ++g) {
            float iv[4]; int ivd;
            if (g == 0) {
                #pragma unroll
                for (int t = 0; t < 4; ++t) iv[t] = cv[t];
                ivd = cd;
            } else {
                const int sl = m + (g - 1) * 16;
                #pragma unroll
                for (int t = 0; t < 4; ++t) iv[t] = __shfl(tl_[t], sl, 64);
                ivd = __shfl(td_, (g - 1) * 16, 64);
            }
            const int hdg = __shfl(hd, g * 16, 64);
            const bool mine = (q == g);
            if (ivd == hdg) {
                if (mine) {
                    if (pure) {
                        #pragma unroll
                        for (int t = 0; t < 4; ++t) tl_[t] += iv[t];
                    } else {
                        #pragma unroll
                        for (int t = 0; t < 4; ++t) head[t] += iv[t];
                    }
                }
            } else {
                if (g == 0) {
                    if (q == 0 && cd >= 0) FLUSH(cd, iv);
                } else {
                    if (q == g - 1) FLUSH(td_, tl_);
                }
            }
            if (mine && !pure) FLUSH(hd, head);
        }
        // new carry = tail of group 3
        #pragma unroll
        for (int t = 0; t < 4; ++t) cv[t] = __shfl(tl_[t], m + 48, 64);
        cd = __shfl(td_, 48, 64);

        // rotate prefetched state
        #pragma unroll
        for (int t = 0; t < 4; ++t) ea[t] = ean[t];
        xa = xan; xb = xbn;
        pvB = pvN;
    }
    // final carry flush
    if (q == 0 && cd >= 0) {
        atomf(agg + (size_t)cd * 64 + m,      cv[0]);
        atomf(agg + (size_t)cd * 64 + m + 16, cv[1]);
        atomf(agg + (size_t)cd * 64 + m + 32, cv[2]);
        atomf(agg + (size_t)cd * 64 + m + 48, cv[3]);
    }
    #undef FLUSH
}

// ===========================================================================
// Fallback (ws too small): unsorted, plain atomics.
// ===========================================================================
__global__ __launch_bounds__(256)
void edge_kernel_unsorted(const float* __restrict__ x,
                          const int* __restrict__ src,
                          const int* __restrict__ dst,
                          const float* __restrict__ eattr,
                          const float* __restrict__ We,
                          const float* __restrict__ be,
                          const float* __restrict__ Wm,
                          const float* __restrict__ bm,
                          float* __restrict__ agg)
{
    __shared__ float ltile[4][16 * 68];
    const int lane = threadIdx.x & 63;
    const int wid  = threadIdx.x >> 6;
    const int m = lane & 15;
    const int q = lane >> 4;
    float* tile = ltile[wid];

    short8 wef[2][4], wmf[2][4];
    float bev[4], bmv[4];
    #pragma unroll
    for (int kh = 0; kh < 2; ++kh)
        #pragma unroll
        for (int t = 0; t < 4; ++t) {
            BF8U fe, fm;
            #pragma unroll
            for (int p = 0; p < 4; ++p) {
                const int k = kh * 32 + q * 8 + p * 2;
                const int n = m + 16 * t;
                fe.u[p] = pk_bf2(We[k * 64 + n], We[(k + 1) * 64 + n]);
                fm.u[p] = pk_bf2(Wm[k * 64 + n], Wm[(k + 1) * 64 + n]);
            }
            wef[kh][t] = fe.v; wmf[kh][t] = fm.v;
        }
    #pragma unroll
    for (int t = 0; t < 4; ++t) { bev[t] = be[m + 16 * t]; bmv[t] = bm[m + 16 * t]; }

    const int n_tiles = NE / 16;
    const int stride = gridDim.x * 4;
    for (int tl = blockIdx.x * 4 + wid; tl < n_tiles; tl += stride) {
        const int e0 = tl * 16;
        short8 a1[2];
        #pragma unroll
        for (int kh = 0; kh < 2; ++kh) {
            const float* p = eattr + (size_t)(e0 + m) * 64 + kh * 32 + q * 8;
            F4 v0, v1; v0.v = *(const floatx4*)p; v1.v = *(const floatx4*)(p + 4);
            BF8U f;
            f.u[0] = pk_bf2(v0.f[0], v0.f[1]);
            f.u[1] = pk_bf2(v0.f[2], v0.f[3]);
            f.u[2] = pk_bf2(v1.f[0], v1.f[1]);
            f.u[3] = pk_bf2(v1.f[2], v1.f[3]);
            a1[kh] = f.v;
        }
        floatx4 acc[4];
        #pragma unroll
        for (int t = 0; t < 4; ++t) acc[t] = (floatx4){0.f, 0.f, 0.f, 0.f};
        #pragma unroll
        for (int kh = 0; kh < 2; ++kh)
            #pragma unroll
            for (int t = 0; t < 4; ++t)
                acc[t] = __builtin_amdgcn_mfma_f32_16x16x32_bf16(a1[kh], wef[kh][t], acc[t], 0, 0, 0);
        #pragma unroll
        for (int t = 0; t < 4; ++t)
            #pragma unroll
            for (int r = 0; r < 4; ++r)
                tile[(q * 4 + r) * 68 + m + 16 * t] = silu_f(acc[t][r] + bev[t]);
        __asm__ volatile("s_waitcnt lgkmcnt(0)" ::: "memory");
        const int sn = src[e0 + m];
        short8 a2[2];
        {
            const float* lp = &tile[m * 68 + q * 8];
            const float* xp = x + (size_t)sn * 64 + q * 8;
            F4 a, b, c, d, X0, X1, X2, X3;
            a.v = *(const floatx4*)lp;        b.v = *(const floatx4*)(lp + 4);
            c.v = *(const floatx4*)(lp + 32); d.v = *(const floatx4*)(lp + 36);
            X0.v = *(const floatx4*)xp;        X1.v = *(const floatx4*)(xp + 4);
            X2.v = *(const floatx4*)(xp + 32); X3.v = *(const floatx4*)(xp + 36);
            BF8U f0, f1;
            f0.u[0] = pk_bf2(fmaxf(a.f[0]+X0.f[0],0.f), fmaxf(a.f[1]+X0.f[1],0.f));
            f0.u[1] = pk_bf2(fmaxf(a.f[2]+X0.f[2],0.f), fmaxf(a.f[3]+X0.f[3],0.f));
            f0.u[2] = pk_bf2(fmaxf(b.f[0]+X1.f[0],0.f), fmaxf(b.f[1]+X1.f[1],0.f));
            f0.u[3] = pk_bf2(fmaxf(b.f[2]+X1.f[2],0.f), fmaxf(b.f[3]+X1.f[3],0.f));
            f1.u[0] = pk_bf2(fmaxf(c.f[0]+X2.f[0],0.f), fmaxf(c.f[1]+X2.f[1],0.f));
            f1.u[1] = pk_bf2(fmaxf(c.f[2]+X2.f[2],0.f), fmaxf(c.f[3]+X2.f[3],0.f));
            f1.u[2] = pk_bf2(fmaxf(d.f[0]+X3.f[0],0.f), fmaxf(d.f[1]+X3.f[1],0.f));
            f1.u[3] = pk_bf2(fmaxf(d.f[2]+X3.f[2],0.f), fmaxf(d.f[3]+X3.f[3],0.f));
            a2[0] = f0.v; a2[1] = f1.v;
        }
        #pragma unroll
        for (int t = 0; t < 4; ++t) acc[t] = (floatx4){0.f, 0.f, 0.f, 0.f};
        #pragma unroll
        for (int kh = 0; kh < 2; ++kh)
            #pragma unroll
            for (int t = 0; t < 4; ++t)
                acc[t] = __builtin_amdgcn_mfma_f32_16x16x32_bf16(a2[kh], wmf[kh][t], acc[t], 0, 0, 0);
        int dn[4];
        #pragma unroll
        for (int r = 0; r < 4; ++r) dn[r] = dst[e0 + q * 4 + r];
        #pragma unroll
        for (int t = 0; t < 4; ++t)
            #pragma unroll
            for (int r = 0; r < 4; ++r)
                atomf(agg + (size_t)dn[r] * 64 + m + 16 * t, silu_f(acc[t][r] + bmv[t]));
    }
}

// ===========================================================================
// Stats: per-graph sum/sumsq/count over pre = agg + (1+eps)*x (n2g sorted).
// ===========================================================================
#define STATS_WAVES 4096
__global__ __launch_bounds__(256)
void stats_kernel(const float* __restrict__ agg,
                  const float* __restrict__ x,
                  const int* __restrict__ n2g,
                  const float* __restrict__ eps,
                  float* __restrict__ gsum,
                  float* __restrict__ gss,
                  float* __restrict__ gcnt)
{
    const int lane = threadIdx.x & 63;
    const int wid  = threadIdx.x >> 6;
    const int w    = blockIdx.x * 4 + wid;
    const int chunk = (NN + STATS_WAVES - 1) / STATS_WAVES;
    const int n0 = w * chunk;
    const int n1 = min(NN, n0 + chunk);
    if (n0 >= n1) return;
    const float k = 1.0f + eps[0];

    int   curg = n2g[n0];
    float s = 0.f, ss = 0.f, rc = 0.f;
    for (int n = n0; n < n1; ++n) {
        const int g = n2g[n];
        if (g != curg) {
            float a = s, b = ss;
            #pragma unroll
            for (int off = 32; off > 0; off >>= 1) {
                a += __shfl_down(a, off, 64);
                b += __shfl_down(b, off, 64);
            }
            if (lane == 0) {
                atomf(&gsum[curg], a);
                atomf(&gss[curg], b);
                atomf(&gcnt[curg], rc);
            }
            s = 0.f; ss = 0.f; rc = 0.f; curg = g;
        }
        const float pre = agg[(size_t)n * 64 + lane] + k * x[(size_t)n * 64 + lane];
        s += pre; ss += pre * pre; rc += (lane == 0) ? 1.0f : 0.0f;
    }
    float a = s, b = ss;
    #pragma unroll
    for (int off = 32; off > 0; off >>= 1) {
        a += __shfl_down(a, off, 64);
        b += __shfl_down(b, off, 64);
    }
    if (lane == 0) {
        atomf(&gsum[curg], a);
        atomf(&gss[curg], b);
        atomf(&gcnt[curg], rc);
    }
}

// ===========================================================================
// Norm + residual + relu, in place over agg (== d_out).
// ===========================================================================
__global__ __launch_bounds__(256)
void norm_kernel(const float* __restrict__ x,
                 const int* __restrict__ n2g,
                 const float* __restrict__ eps,
                 const float* __restrict__ gamma,
                 const float* __restrict__ beta,
                 const float* __restrict__ gsum,
                 const float* __restrict__ gss,
                 const float* __restrict__ gcnt,
                 float* __restrict__ out)
{
    const float k = 1.0f + eps[0];
    const int total = NN * 16;
    for (int idx = blockIdx.x * blockDim.x + threadIdx.x; idx < total;
         idx += gridDim.x * blockDim.x) {
        const int n  = idx >> 4;
        const int c4 = (idx & 15) * 4;
        const int g  = n2g[n];
        const float cnt  = fmaxf(gcnt[g] * 64.0f, 1.0f);
        const float mean = gsum[g] / cnt;
        const float var  = gss[g] / cnt - mean * mean;
        const float rsig = rsqrtf(var + LN_EPS);
        F4 a, xv, o;
        a.v  = *(const floatx4*)&out[(size_t)n * 64 + c4];
        xv.v = *(const floatx4*)&x[(size_t)n * 64 + c4];
        #pragma unroll
        for (int j = 0; j < 4; ++j) {
            const float pre = a.f[j] + k * xv.f[j];
            const float v = (pre - mean) * rsig * gamma[c4 + j] + beta[c4 + j] + xv.f[j];
            o.f[j] = fmaxf(v, 0.0f);
        }
        *(floatx4*)&out[(size_t)n * 64 + c4] = o.v;
    }
}

extern "C" void kernel_launch(void* const* d_in, const int* in_sizes, int n_in,
                              void* d_out, int out_size, void* d_ws, size_t ws_size,
                              hipStream_t stream)
{
    const float* x      = (const float*)d_in[0];
    const int*   ei     = (const int*)  d_in[1];
    const float* eattr  = (const float*)d_in[2];
    const int*   n2g    = (const int*)  d_in[3];
    // branch-1 params (d_in[4..10]) are dead: conv1's result is overwritten by
    // conv2(x, ...) in the reference. Only branch 2 affects the output.
    const float* We2    = (const float*)d_in[11];
    const float* be2    = (const float*)d_in[12];
    const float* Wm2    = (const float*)d_in[13];
    const float* bm2    = (const float*)d_in[14];
    const float* eps2   = (const float*)d_in[15];
    const float* gamma2 = (const float*)d_in[16];
    const float* beta2  = (const float*)d_in[17];
    const int* src = ei;
    const int* dst = ei + NE;

    float* out  = (float*)d_out;           // doubles as agg scratch
    // ws: gsum[512] gss[512] gcnt[512] | bsums[128] | cnt[NN] | dsts_s[NE]
    //     | ps[2*NE] | x_bf[NN*32]
    float* gsum = (float*)d_ws;
    float* gss  = gsum + NG;
    float* gcnt = gss + NG;
    int*  bsums  = (int*)(gcnt + NG);
    int*  cnt    = bsums + 128;
    int*  dsts_s = cnt + NN;
    int2* ps     = (int2*)(dsts_s + NE);
    unsigned* x_bf = (unsigned*)(ps + NE);
    const size_t ws_need = (size_t)(3 * NG + 128 + NN + NE + 2 * (size_t)NE
                                    + (size_t)NN * 32) * 4;
    const bool do_sort = ws_size >= ws_need;

    hipMemsetAsync(d_out, 0, (size_t)NN * 64 * sizeof(float), stream);
    if (do_sort) {
        hipMemsetAsync(d_ws, 0, (size_t)(3 * NG + 128 + NN) * 4, stream);
        xconv_hist_kernel<<<dim3(512), dim3(256), 0, stream>>>(x, x_bf, dst, cnt);
        scan_partial_kernel<<<dim3(SCAN_NB), dim3(256), 0, stream>>>(cnt, bsums);
        scan_top_kernel<<<dim3(1), dim3(128), 0, stream>>>(bsums);
        scan_final_kernel<<<dim3(SCAN_NB), dim3(256), 0, stream>>>(cnt, bsums);
        scatter_kernel<<<dim3(512), dim3(256), 0, stream>>>(src, dst, cnt, ps, dsts_s);
        edge_kernel_sorted<<<dim3(EK_BLOCKS), dim3(256), 0, stream>>>(
            x_bf, ps, dsts_s, eattr, We2, be2, Wm2, bm2, out);
    } else {
        hipMemsetAsync(d_ws, 0, 3 * NG * sizeof(float), stream);
        edge_kernel_unsorted<<<dim3(2048), dim3(256), 0, stream>>>(
            x, src, dst, eattr, We2, be2, Wm2, bm2, out);
    }
    stats_kernel<<<dim3(STATS_WAVES / 4), dim3(256), 0, stream>>>(
        out, x, n2g, eps2, gsum, gss, gcnt);
    norm_kernel<<<dim3(1024), dim3(256), 0, stream>>>(
        x, n2g, eps2, gamma2, beta2, gsum, gss, gcnt, out);
}